// Round 10
// baseline (398.714 us; speedup 1.0000x reference)
//
#include <hip/hip_runtime.h>
#include <stdint.h>

#define NNODES 64
#define NVIS   16
#define NHID   48
#define NSTEPS 20
#define BATCH  65536
#define EDIM   512

typedef float f32x2 __attribute__((ext_vector_type(2)));
typedef float f32x4 __attribute__((ext_vector_type(4)));

// ---- VOP3P packed f32 helpers: per-component IEEE RN, bit-identical to scalar ----
__device__ __forceinline__ f32x2 pk_fma_lo(f32x2 s, f32x2 w, f32x2 c) {
  f32x2 d;
  asm("v_pk_fma_f32 %0, %1, %2, %3 op_sel:[0,0,0] op_sel_hi:[1,0,1]"
      : "=v"(d) : "v"(s), "v"(w), "v"(c));
  return d;
}
__device__ __forceinline__ f32x2 pk_fma_hi(f32x2 s, f32x2 w, f32x2 c) {
  f32x2 d;
  asm("v_pk_fma_f32 %0, %1, %2, %3 op_sel:[0,1,0] op_sel_hi:[1,1,1]"
      : "=v"(d) : "v"(s), "v"(w), "v"(c));
  return d;
}
__device__ __forceinline__ f32x2 pk_fma2(f32x2 a, f32x2 b, f32x2 c) {
  f32x2 d;
  asm("v_pk_fma_f32 %0, %1, %2, %3" : "=v"(d) : "v"(a), "v"(b), "v"(c));
  return d;
}
__device__ __forceinline__ f32x2 pk_mul2(f32x2 a, f32x2 b) {
  f32x2 d;
  asm("v_pk_mul_f32 %0, %1, %2" : "=v"(d) : "v"(a), "v"(b));
  return d;
}
__device__ __forceinline__ f32x2 pk_add2(f32x2 a, f32x2 b) {
  f32x2 d;
  asm("v_pk_add_f32 %0, %1, %2" : "=v"(d) : "v"(a), "v"(b));
  return d;
}
__device__ __forceinline__ f32x2 pk_sub2(f32x2 a, f32x2 b) {   // a - b
  f32x2 d;
  asm("v_pk_add_f32 %0, %1, %2 neg_lo:[0,1] neg_hi:[0,1]" : "=v"(d) : "v"(a), "v"(b));
  return d;
}
__device__ __forceinline__ f32x2 pk_negsub2(f32x2 a, f32x2 b) { // -a - b
  f32x2 d;
  asm("v_pk_add_f32 %0, %1, %2 neg_lo:[1,1] neg_hi:[1,1]" : "=v"(d) : "v"(a), "v"(b));
  return d;
}

// ---- exact byte->float converts (0/1 -> 0.0f/1.0f): one VALU each ----
__device__ __forceinline__ float cvt_ub0(uint32_t d) {
  float f; asm("v_cvt_f32_ubyte0 %0, %1" : "=v"(f) : "v"(d)); return f;
}
__device__ __forceinline__ float cvt_ub1(uint32_t d) {
  float f; asm("v_cvt_f32_ubyte1 %0, %1" : "=v"(f) : "v"(d)); return f;
}
__device__ __forceinline__ float cvt_ub2(uint32_t d) {
  float f; asm("v_cvt_f32_ubyte2 %0, %1" : "=v"(f) : "v"(d)); return f;
}
__device__ __forceinline__ float cvt_ub3(uint32_t d) {
  float f; asm("v_cvt_f32_ubyte3 %0, %1" : "=v"(f) : "v"(d)); return f;
}

// ---------------- Threefry-2x32 (20 rounds), exactly as JAX/random123 ----------------
__device__ __forceinline__ void tf2x32(uint32_t k0, uint32_t k1,
                                       uint32_t x0, uint32_t x1,
                                       uint32_t& o0, uint32_t& o1) {
  const uint32_t ks0 = k0, ks1 = k1, ks2 = k0 ^ k1 ^ 0x1BD11BDAu;
  x0 += ks0; x1 += ks1;
  const int rotA[4] = {13, 15, 26, 6};
  const int rotB[4] = {17, 29, 16, 24};
#pragma unroll
  for (int i = 0; i < 5; ++i) {
#pragma unroll
    for (int r = 0; r < 4; ++r) {
      const int rot = (i & 1) ? rotB[r] : rotA[r];
      x0 += x1;
      x1 = __builtin_rotateleft32(x1, rot);
      x1 ^= x0;
    }
    const uint32_t i0 = (i == 0 || i == 3) ? ks1 : (i == 1 || i == 4) ? ks2 : ks0;
    const uint32_t i1 = (i == 0 || i == 3) ? ks2 : (i == 1 || i == 4) ? ks0 : ks1;
    x0 += i0;
    x1 += i1 + (uint32_t)(i + 1);
  }
  o0 = x0; o1 = x1;
}

__device__ __forceinline__ uint32_t rbits32(uint32_t k0, uint32_t k1, uint32_t n) {
  uint32_t a, b;
  tf2x32(k0, k1, 0u, n, a, b);
  return a ^ b;
}

// ---- sigmoid: 1/(1+exp(-a)), XLA CPU Cephes exp, VOP3P-packed (bit-identical) ----
__device__ __forceinline__ f32x2 sigmoid2_pk(f32x2 a) {
#pragma clang fp contract(off)
  const f32x2 cL2En  = (f32x2)(-1.44269504088896341f);
  const f32x2 cHalf  = (f32x2)0.5f;
  const f32x2 cLn2Hi = (f32x2)0.693359375f;
  const f32x2 cLn2Lo = (f32x2)(-2.12194440e-4f);
  const f32x2 c0 = (f32x2)1.9875691500e-4f, c1 = (f32x2)1.3981999507e-3f;
  const f32x2 c2 = (f32x2)8.3334519073e-3f, c3 = (f32x2)4.1665795894e-2f;
  const f32x2 c4 = (f32x2)1.6666665459e-1f, c5 = (f32x2)5.0000001201e-1f;
  const f32x2 cOne = (f32x2)1.0f;

  f32x2 t = pk_fma2(a, cL2En, cHalf);   // fma(-a, log2e, 0.5): identical exact product
  f32x2 fx; fx.x = floorf(t.x); fx.y = floorf(t.y);
  f32x2 tmp = pk_mul2(fx, cLn2Hi);      // separate mul (NOT fused), like XLA
  f32x2 z   = pk_mul2(fx, cLn2Lo);
  f32x2 xr  = pk_negsub2(a, tmp);       // (-a) - tmp
  xr = pk_sub2(xr, z);
  f32x2 zz = pk_mul2(xr, xr);
  f32x2 y = pk_fma2(xr, c0, c1);
  y = pk_fma2(y, xr, c2);
  y = pk_fma2(y, xr, c3);
  y = pk_fma2(y, xr, c4);
  y = pk_fma2(y, xr, c5);
  y = pk_fma2(y, zz, xr);
  y = pk_add2(y, cOne);
  int mx = (int)fx.x, my = (int)fx.y;   // fx integral -> trunc == value
  f32x2 e;
  e.x = __int_as_float((mx + 127) << 23);
  e.y = __int_as_float((my + 127) << 23);
  f32x2 ex = pk_mul2(y, e);             // exp(-a), exact scale by 2^m
  f32x2 den = pk_add2(ex, cOne);
  f32x2 r;
  r.x = 1.0f / den.x;                   // IEEE correctly-rounded div
  r.y = 1.0f / den.y;
  return r;
}

// byte-state dual dot: state dword per node = {r0,r1,r2,r3} bytes in {0,1}.
// Unpack via v_cvt_f32_ubyte (exact), then the SAME sequential-k pk_fma chains as
// before — bit-identical rounding to the reference. LDS: 12 uniform b128 reads only.
__device__ __forceinline__ void dot_bytes(const uint4* st,
                                          const f32x2* wp, f32x2 a16A, f32x2 a16B,
                                          f32x2& oA, f32x2& oB) {
  f32x2 accA = a16A, accB = a16B;
#pragma unroll
  for (int i = 0; i < 12; ++i) {
    uint4 q = st[i];
    {
      f32x2 sA; sA.x = cvt_ub0(q.x); sA.y = cvt_ub1(q.x);
      f32x2 sB; sB.x = cvt_ub2(q.x); sB.y = cvt_ub3(q.x);
      accA = pk_fma_lo(sA, wp[2 * i], accA);      // k = 16 + 4i
      accB = pk_fma_lo(sB, wp[2 * i], accB);
    }
    {
      f32x2 sA; sA.x = cvt_ub0(q.y); sA.y = cvt_ub1(q.y);
      f32x2 sB; sB.x = cvt_ub2(q.y); sB.y = cvt_ub3(q.y);
      accA = pk_fma_hi(sA, wp[2 * i], accA);      // k = 17 + 4i
      accB = pk_fma_hi(sB, wp[2 * i], accB);
    }
    {
      f32x2 sA; sA.x = cvt_ub0(q.z); sA.y = cvt_ub1(q.z);
      f32x2 sB; sB.x = cvt_ub2(q.z); sB.y = cvt_ub3(q.z);
      accA = pk_fma_lo(sA, wp[2 * i + 1], accA);  // k = 18 + 4i
      accB = pk_fma_lo(sB, wp[2 * i + 1], accB);
    }
    {
      f32x2 sA; sA.x = cvt_ub0(q.w); sA.y = cvt_ub1(q.w);
      f32x2 sB; sB.x = cvt_ub2(q.w); sB.y = cvt_ub3(q.w);
      accA = pk_fma_hi(sA, wp[2 * i + 1], accA);  // k = 19 + 4i
      accB = pk_fma_hi(sB, wp[2 * i + 1], accB);
    }
  }
  oA = accA; oB = accB;
}

// ---------------- stage 1: partial column sums of embedding ----------------
__global__ __launch_bounds__(512) void colsum_kernel(const float4* __restrict__ emb4,
                                                     float4* __restrict__ partials4,
                                                     int nblk) {
  __shared__ float4 red[4][128];
  const int t = threadIdx.x;
  const int c4 = t & 127, rs = t >> 7;
  float4 acc = make_float4(0.f, 0.f, 0.f, 0.f);
  const int stride = nblk * 4;
  for (int r = blockIdx.x * 4 + rs; r < BATCH; r += stride) {
    float4 v = emb4[(size_t)r * 128 + c4];
    acc.x += v.x; acc.y += v.y; acc.z += v.z; acc.w += v.w;
  }
  red[rs][c4] = acc;
  __syncthreads();
  if (rs == 0) {
    float4 a = red[0][c4], b = red[1][c4], c = red[2][c4], d = red[3][c4];
    float4 s;
    s.x = (a.x + b.x) + (c.x + d.x);
    s.y = (a.y + b.y) + (c.y + d.y);
    s.z = (a.z + b.z) + (c.z + d.z);
    s.w = (a.w + b.w) + (c.w + d.w);
    partials4[(size_t)blockIdx.x * 128 + c4] = s;
  }
}

// ---------------- stage 2: reduce nblk slots -> g2 slots ----------------
__global__ __launch_bounds__(512) void reduce_kernel(const float* __restrict__ partials,
                                                     float* __restrict__ level2, int per) {
  const int t = threadIdx.x;
  float a = 0.0f;
  const int s0 = blockIdx.x * per;
  for (int s = s0; s < s0 + per; ++s) a += partials[(size_t)s * EDIM + t];
  level2[(size_t)blockIdx.x * EDIM + t] = a;
}

// ---------------- stage 3: finish b, derive all threefry keys ----------------
__global__ __launch_bounds__(512) void prep_kernel(const float* __restrict__ pca,
                                                   const float* __restrict__ level2, int g2,
                                                   float* __restrict__ bvec,
                                                   unsigned* __restrict__ keys) {
  __shared__ float cs[EDIM];
  int t = threadIdx.x;
  float a = 0.0f;
  for (int i = 0; i < g2; ++i) a += level2[(size_t)i * EDIM + t];
  cs[t] = a;
  __syncthreads();
  if (t < NNODES) {
    float bj = 0.0f;
    if (t < NVIS) {
      for (int e = 0; e < EDIM; ++e) bj = fmaf(cs[e], pca[e * NVIS + t], bj);
      bj *= (1.0f / 65536.0f);
    }
    bvec[t] = bj;
  }
  if (t == 0) {
    uint32_t ki0, ki1, ks0, ks1;
    tf2x32(0u, 42u, 0u, 0u, ki0, ki1);          // k_init
    tf2x32(0u, 42u, 0u, 1u, ks0, ks1);          // k_scan
    keys[0] = ki0; keys[1] = ki1;
    for (int s = 0; s < NSTEPS; ++s) {
      uint32_t y0, y1;
      tf2x32(ks0, ks1, 0u, (uint32_t)s, y0, y1);
      keys[2 + 2 * s] = y0;
      keys[3 + 2 * s] = y1;
    }
  }
}

// ---------------- gibbs chain + energy: 1 wave = 4 rows, byte-packed state ------------
// R5 framing, but state lives in LDS as ONE u32 per node (4 row-bytes in {0,1}).
// Dot LDS traffic: 48 uniform b128/step -> 12 (4x less return-bus). Unpack via
// v_cvt_f32_ubyte (exact). All arithmetic bit-identical to R5.
__global__ __launch_bounds__(256, 4) void gibbs_kernel(const float* __restrict__ reward,
                                                       const float* __restrict__ quadratic,
                                                       const float* __restrict__ bvec,
                                                       const unsigned* __restrict__ keys,
                                                       float* __restrict__ out) {
#pragma clang fp contract(off)
  __shared__ float Wl[NNODES][NNODES];                 // 16KB (live: wp reloads legal)
  __shared__ float ubuf[4][4 * NHID];                  // 3KB u staging [row][node']
  __shared__ alignas(16) uint32_t sbyte[4][NHID];      // 768B state: dword/node = 4 rows

  const int tid = threadIdx.x;
  for (int i = tid; i < NNODES * NNODES; i += 256) {
    int k = i >> 6, j = i & 63;
    Wl[k][j] = quadratic[i] + quadratic[j * NNODES + k];  // exact f32 add
  }
  __syncthreads();                                        // W tile ready

  const int wave = tid >> 6, lane = tid & 63;
  const int gw = blockIdx.x * 4 + wave;
  const int r0 = gw * 4;

  const float4 rw4 = ((const float4*)reward)[gw];
  const float bj = bvec[lane];
  f32x2 svA = sigmoid2_pk((f32x2){rw4.x * 2.0f, rw4.y * 2.0f});
  f32x2 svB = sigmoid2_pk((f32x2){rw4.z * 2.0f, rw4.w * 2.0f});

  // W column: hidden rows as pairs; visible prefix folded into acc16 (k=0..15 in order)
  f32x2 wp[24];
#pragma unroll
  for (int i = 0; i < 24; ++i) {
    f32x2 w; w.x = Wl[16 + 2 * i][lane]; w.y = Wl[17 + 2 * i][lane];
    wp[i] = w;
  }
  f32x2 acc16A = (f32x2)0.0f, acc16B = (f32x2)0.0f;
#pragma unroll
  for (int i = 0; i < 8; ++i) {
    f32x2 w; w.x = Wl[2 * i][lane]; w.y = Wl[2 * i + 1][lane];
    acc16A = pk_fma_lo(svA, w, acc16A);
    acc16A = pk_fma_hi(svA, w, acc16A);
    acc16B = pk_fma_lo(svB, w, acc16B);
    acc16B = pk_fma_hi(svB, w, acc16B);
  }

  float* ubw = ubuf[wave];
  uint32_t* sw32 = sbyte[wave];
  const uint4* stq = (const uint4*)sw32;

  // producer routing: draw idx = c*64 + lane -> (row rr, hidden node jj); step-invariant
  uint32_t nn[3];            // scan counters: (r0+rr)*64 + 16 + jj   (shape B x 64)
  uint32_t ni[3];            // init counters: (r0+rr)*48 + jj        (shape B x 48)
  float*   uw[3];            // u staging slots [rr*48 + jj] == [idx] (stride-1)
  int      sb_off[3];        // init state byte offsets jj*4 + rr
#pragma unroll
  for (int c = 0; c < 3; ++c) {
    int idx = c * 64 + lane;
    int rr = (idx * 683) >> 15;            // idx / 48 for idx < 192
    int jj = idx - rr * 48;
    nn[c] = (uint32_t)((r0 + rr) * NNODES + NVIS + jj);
    ni[c] = (uint32_t)((r0 + rr) * NHID + jj);
    uw[c] = ubw + idx;                     // rr*48 + jj == idx
    sb_off[c] = jj * 4 + rr;
  }

  const bool isvis = (lane < NVIS);
  const int jc = isvis ? 0 : lane - NVIS;

  // hidden0 = bernoulli(k_init, 0.5): bit = (rbits32 >> 31) == 0; write state BYTES
  {
    const uint32_t ki0 = keys[0], ki1 = keys[1];
    volatile uint8_t* sb8 = (volatile uint8_t*)sw32;   // byte view of state dwords
#pragma unroll
    for (int c = 0; c < 3; ++c) {
      uint32_t b = rbits32(ki0, ki1, ni[c]);
      sb8[sb_off[c]] = (uint8_t)((b >> 31) ^ 1u);      // u<0.5 <=> top bit 0 -> s=1
    }
  }

  uint32_t dcur = 0;                       // this lane's node state dword (hidden lanes)
  const uint2* kbuf = (const uint2*)(keys + 2);
  uint2 kk = kbuf[0];
#pragma unroll 1
  for (int t = 0; t < NSTEPS; ++t) {
    uint2 kn = kbuf[(t + 1 < NSTEPS) ? t + 1 : t];
    // 3 independent cipher chains (compiler interleaves for ILP)
    uint32_t b0 = rbits32(kk.x, kk.y, nn[0]);
    uint32_t b1 = rbits32(kk.x, kk.y, nn[1]);
    uint32_t b2 = rbits32(kk.x, kk.y, nn[2]);
    *uw[0] = __uint_as_float((b0 >> 9) | 0x3f800000u) - 1.0f;  // exact u01
    *uw[1] = __uint_as_float((b1 >> 9) | 0x3f800000u) - 1.0f;
    *uw[2] = __uint_as_float((b2 >> 9) | 0x3f800000u) - 1.0f;

    f32x2 aA, aB;
    dot_bytes(stq, wp, acc16A, acc16B, aA, aB);
    f32x2 pA = sigmoid2_pk(aA);            // b adds 0 to hidden units
    f32x2 pB = sigmoid2_pk(aB);

    // consumer: 4 stride-1 u reads, compare, pack 4 result bytes, 1 dword write
    f32x2 uA; uA.x = ubw[jc];            uA.y = ubw[NHID + jc];
    f32x2 uB; uB.x = ubw[2 * NHID + jc]; uB.y = ubw[3 * NHID + jc];
    if (!isvis) {
      uint32_t e0 = (uA.x < pA.x) ? 1u : 0u;
      uint32_t e1 = (uA.y < pA.y) ? 1u : 0u;
      uint32_t e2 = (uB.x < pB.x) ? 1u : 0u;
      uint32_t e3 = (uB.y < pB.y) ? 1u : 0u;
      dcur = e0 | (e1 << 8) | (e2 << 16) | (e3 << 24);
      sw32[jc] = dcur;
    }
    kk = kn;
  }

  // energy: adjusted[r] = reward[r] + sum_j s_j*(0.5*a_j + b_j)   (loose tolerance)
  f32x2 aA, aB;
  dot_bytes(stq, wp, acc16A, acc16B, aA, aB);
  f32x2 scurA = svA, scurB = svB;
  if (!isvis) {
    scurA.x = cvt_ub0(dcur); scurA.y = cvt_ub1(dcur);
    scurB.x = cvt_ub2(dcur); scurB.y = cvt_ub3(dcur);
  }
  f32x2 bj2; bj2.x = bj; bj2.y = bj;
  const f32x2 half2 = (f32x2)0.5f;
  f32x2 cA = pk_mul2(scurA, pk_fma2(half2, aA, bj2));
  f32x2 cB = pk_mul2(scurB, pk_fma2(half2, aB, bj2));
  float c0 = cA.x, c1 = cA.y, c2 = cB.x, c3 = cB.y;
#pragma unroll
  for (int off = 32; off; off >>= 1) {
    c0 += __shfl_xor(c0, off);
    c1 += __shfl_xor(c1, off);
    c2 += __shfl_xor(c2, off);
    c3 += __shfl_xor(c3, off);
  }
  if (lane == 0) {
    ((float4*)out)[gw] = make_float4(rw4.x + c0, rw4.y + c1, rw4.z + c2, rw4.w + c3);
  }
}

extern "C" void kernel_launch(void* const* d_in, const int* in_sizes, int n_in,
                              void* d_out, int out_size, void* d_ws, size_t ws_size,
                              hipStream_t stream) {
  const float* emb    = (const float*)d_in[0];
  const float* reward = (const float*)d_in[1];
  const float* pca    = (const float*)d_in[2];
  const float* quad   = (const float*)d_in[3];
  float* out = (float*)d_out;

  int nblk = 1024;
  while (nblk > 4 &&
         ws_size < (size_t)nblk * EDIM * 4 + (size_t)64 * EDIM * 4 + 4096)
    nblk >>= 1;
  const int g2  = (nblk >= 64) ? 64 : nblk;
  const int per = nblk / g2;

  float*    partials = (float*)d_ws;
  float*    level2   = partials + (size_t)nblk * EDIM;
  float*    bvec     = level2 + (size_t)64 * EDIM;
  unsigned* keys     = (unsigned*)(bvec + NNODES);

  colsum_kernel<<<nblk, 512, 0, stream>>>((const float4*)emb, (float4*)partials, nblk);
  reduce_kernel<<<g2, 512, 0, stream>>>(partials, level2, per);
  prep_kernel<<<1, 512, 0, stream>>>(pca, level2, g2, bvec, keys);
  gibbs_kernel<<<BATCH / 16, 256, 0, stream>>>(reward, quad, bvec, keys, out);
}

// Round 11
// 304.575 us; speedup vs baseline: 1.3091x; 1.3091x over previous
//
#include <hip/hip_runtime.h>
#include <stdint.h>

#define NNODES 64
#define NVIS   16
#define NHID   48
#define NSTEPS 20
#define BATCH  65536
#define EDIM   512

typedef float f32x2 __attribute__((ext_vector_type(2)));
typedef float f32x4 __attribute__((ext_vector_type(4)));

// ---- VOP3P packed f32 helpers: per-component IEEE RN, bit-identical to scalar ----
__device__ __forceinline__ f32x2 pk_fma_lo(f32x2 s, f32x2 w, f32x2 c) {
  f32x2 d;
  asm("v_pk_fma_f32 %0, %1, %2, %3 op_sel:[0,0,0] op_sel_hi:[1,0,1]"
      : "=v"(d) : "v"(s), "v"(w), "v"(c));
  return d;
}
__device__ __forceinline__ f32x2 pk_fma_hi(f32x2 s, f32x2 w, f32x2 c) {
  f32x2 d;
  asm("v_pk_fma_f32 %0, %1, %2, %3 op_sel:[0,1,0] op_sel_hi:[1,1,1]"
      : "=v"(d) : "v"(s), "v"(w), "v"(c));
  return d;
}
__device__ __forceinline__ f32x2 pk_fma2(f32x2 a, f32x2 b, f32x2 c) {
  f32x2 d;
  asm("v_pk_fma_f32 %0, %1, %2, %3" : "=v"(d) : "v"(a), "v"(b), "v"(c));
  return d;
}
__device__ __forceinline__ f32x2 pk_mul2(f32x2 a, f32x2 b) {
  f32x2 d;
  asm("v_pk_mul_f32 %0, %1, %2" : "=v"(d) : "v"(a), "v"(b));
  return d;
}
__device__ __forceinline__ f32x2 pk_add2(f32x2 a, f32x2 b) {
  f32x2 d;
  asm("v_pk_add_f32 %0, %1, %2" : "=v"(d) : "v"(a), "v"(b));
  return d;
}
__device__ __forceinline__ f32x2 pk_sub2(f32x2 a, f32x2 b) {   // a - b
  f32x2 d;
  asm("v_pk_add_f32 %0, %1, %2 neg_lo:[0,1] neg_hi:[0,1]" : "=v"(d) : "v"(a), "v"(b));
  return d;
}
__device__ __forceinline__ f32x2 pk_negsub2(f32x2 a, f32x2 b) { // -a - b
  f32x2 d;
  asm("v_pk_add_f32 %0, %1, %2 neg_lo:[1,1] neg_hi:[1,1]" : "=v"(d) : "v"(a), "v"(b));
  return d;
}

// ---------------- Threefry-2x32 (20 rounds), exactly as JAX/random123 ----------------
__device__ __forceinline__ void tf2x32(uint32_t k0, uint32_t k1,
                                       uint32_t x0, uint32_t x1,
                                       uint32_t& o0, uint32_t& o1) {
  const uint32_t ks0 = k0, ks1 = k1, ks2 = k0 ^ k1 ^ 0x1BD11BDAu;
  x0 += ks0; x1 += ks1;
  const int rotA[4] = {13, 15, 26, 6};
  const int rotB[4] = {17, 29, 16, 24};
#pragma unroll
  for (int i = 0; i < 5; ++i) {
#pragma unroll
    for (int r = 0; r < 4; ++r) {
      const int rot = (i & 1) ? rotB[r] : rotA[r];
      x0 += x1;
      x1 = __builtin_rotateleft32(x1, rot);
      x1 ^= x0;
    }
    const uint32_t i0 = (i == 0 || i == 3) ? ks1 : (i == 1 || i == 4) ? ks2 : ks0;
    const uint32_t i1 = (i == 0 || i == 3) ? ks2 : (i == 1 || i == 4) ? ks0 : ks1;
    x0 += i0;
    x1 += i1 + (uint32_t)(i + 1);
  }
  o0 = x0; o1 = x1;
}

__device__ __forceinline__ uint32_t rbits32(uint32_t k0, uint32_t k1, uint32_t n) {
  uint32_t a, b;
  tf2x32(k0, k1, 0u, n, a, b);
  return a ^ b;
}

// ---- sigmoid: 1/(1+exp(-a)), XLA CPU Cephes exp, VOP3P-packed (bit-identical) ----
__device__ __forceinline__ f32x2 sigmoid2_pk(f32x2 a) {
#pragma clang fp contract(off)
  const f32x2 cL2En  = (f32x2)(-1.44269504088896341f);
  const f32x2 cHalf  = (f32x2)0.5f;
  const f32x2 cLn2Hi = (f32x2)0.693359375f;
  const f32x2 cLn2Lo = (f32x2)(-2.12194440e-4f);
  const f32x2 c0 = (f32x2)1.9875691500e-4f, c1 = (f32x2)1.3981999507e-3f;
  const f32x2 c2 = (f32x2)8.3334519073e-3f, c3 = (f32x2)4.1665795894e-2f;
  const f32x2 c4 = (f32x2)1.6666665459e-1f, c5 = (f32x2)5.0000001201e-1f;
  const f32x2 cOne = (f32x2)1.0f;

  f32x2 t = pk_fma2(a, cL2En, cHalf);   // fma(-a, log2e, 0.5): identical exact product
  f32x2 fx; fx.x = floorf(t.x); fx.y = floorf(t.y);
  f32x2 tmp = pk_mul2(fx, cLn2Hi);      // separate mul (NOT fused), like XLA
  f32x2 z   = pk_mul2(fx, cLn2Lo);
  f32x2 xr  = pk_negsub2(a, tmp);       // (-a) - tmp
  xr = pk_sub2(xr, z);
  f32x2 zz = pk_mul2(xr, xr);
  f32x2 y = pk_fma2(xr, c0, c1);
  y = pk_fma2(y, xr, c2);
  y = pk_fma2(y, xr, c3);
  y = pk_fma2(y, xr, c4);
  y = pk_fma2(y, xr, c5);
  y = pk_fma2(y, zz, xr);
  y = pk_add2(y, cOne);
  int mx = (int)fx.x, my = (int)fx.y;   // fx integral -> trunc == value
  f32x2 e;
  e.x = __int_as_float((mx + 127) << 23);
  e.y = __int_as_float((my + 127) << 23);
  f32x2 ex = pk_mul2(y, e);             // exp(-a), exact scale by 2^m
  f32x2 den = pk_add2(ex, cOne);
  f32x2 r;
  r.x = 1.0f / den.x;                   // IEEE correctly-rounded div
  r.y = 1.0f / den.y;
  return r;
}

// dual hidden dot: rows (r0,r1) in chain A, (r2,r3) in chain B.
// st[j'] = {s[16+j'][r0..r3]}; wp[i] = {W[16+2i][lane], W[17+2i][lane]}.
// Sequential k=16..63, single acc per row, fma — identical rounding to reference.
__device__ __forceinline__ void dot4(const f32x4* st,
                                     const f32x2* wp, f32x2 a16A, f32x2 a16B,
                                     f32x2& oA, f32x2& oB) {
  f32x2 accA = a16A, accB = a16B;
#pragma unroll
  for (int i = 0; i < 24; ++i) {
    f32x4 q0 = st[2 * i];
    f32x4 q1 = st[2 * i + 1];
    f32x2 q0A; q0A.x = q0.x; q0A.y = q0.y;
    f32x2 q0B; q0B.x = q0.z; q0B.y = q0.w;
    f32x2 q1A; q1A.x = q1.x; q1A.y = q1.y;
    f32x2 q1B; q1B.x = q1.z; q1B.y = q1.w;
    accA = pk_fma_lo(q0A, wp[i], accA);   // k = 16+2i
    accA = pk_fma_hi(q1A, wp[i], accA);   // k = 17+2i
    accB = pk_fma_lo(q0B, wp[i], accB);
    accB = pk_fma_hi(q1B, wp[i], accB);
  }
  oA = accA; oB = accB;
}

// ---------------- stage 1: partial column sums of embedding ----------------
__global__ __launch_bounds__(512) void colsum_kernel(const float4* __restrict__ emb4,
                                                     float4* __restrict__ partials4,
                                                     int nblk) {
  __shared__ float4 red[4][128];
  const int t = threadIdx.x;
  const int c4 = t & 127, rs = t >> 7;
  float4 acc = make_float4(0.f, 0.f, 0.f, 0.f);
  const int stride = nblk * 4;
  for (int r = blockIdx.x * 4 + rs; r < BATCH; r += stride) {
    float4 v = emb4[(size_t)r * 128 + c4];
    acc.x += v.x; acc.y += v.y; acc.z += v.z; acc.w += v.w;
  }
  red[rs][c4] = acc;
  __syncthreads();
  if (rs == 0) {
    float4 a = red[0][c4], b = red[1][c4], c = red[2][c4], d = red[3][c4];
    float4 s;
    s.x = (a.x + b.x) + (c.x + d.x);
    s.y = (a.y + b.y) + (c.y + d.y);
    s.z = (a.z + b.z) + (c.z + d.z);
    s.w = (a.w + b.w) + (c.w + d.w);
    partials4[(size_t)blockIdx.x * 128 + c4] = s;
  }
}

// ---------------- stage 2: reduce nblk slots -> g2 slots ----------------
__global__ __launch_bounds__(512) void reduce_kernel(const float* __restrict__ partials,
                                                     float* __restrict__ level2, int per) {
  const int t = threadIdx.x;
  float a = 0.0f;
  const int s0 = blockIdx.x * per;
  for (int s = s0; s < s0 + per; ++s) a += partials[(size_t)s * EDIM + t];
  level2[(size_t)blockIdx.x * EDIM + t] = a;
}

// ---------------- stage 3: finish b, derive all threefry keys ----------------
__global__ __launch_bounds__(512) void prep_kernel(const float* __restrict__ pca,
                                                   const float* __restrict__ level2, int g2,
                                                   float* __restrict__ bvec,
                                                   unsigned* __restrict__ keys) {
  __shared__ float cs[EDIM];
  int t = threadIdx.x;
  float a = 0.0f;
  for (int i = 0; i < g2; ++i) a += level2[(size_t)i * EDIM + t];
  cs[t] = a;
  __syncthreads();
  if (t < NNODES) {
    float bj = 0.0f;
    if (t < NVIS) {
      for (int e = 0; e < EDIM; ++e) bj = fmaf(cs[e], pca[e * NVIS + t], bj);
      bj *= (1.0f / 65536.0f);
    }
    bvec[t] = bj;
  }
  if (t == 0) {
    uint32_t ki0, ki1, ks0, ks1;
    tf2x32(0u, 42u, 0u, 0u, ki0, ki1);          // k_init
    tf2x32(0u, 42u, 0u, 1u, ks0, ks1);          // k_scan
    keys[0] = ki0; keys[1] = ki1;
    for (int s = 0; s < NSTEPS; ++s) {
      uint32_t y0, y1;
      tf2x32(ks0, ks1, 0u, (uint32_t)s, y0, y1);
      keys[2 + 2 * s] = y0;
      keys[3 + 2 * s] = y1;
    }
  }
}

// ---------------- gibbs chain + energy: 1 wave = 4 rows, 3 ciphers/lane/step ----------
// Champion structure (R5, 286us gibbs): split ubuf/sbuf staging, stride-1 u path,
// packed pk_fma dot with LDS-broadcast state, compiler-managed wp/Wl residency.
__global__ __launch_bounds__(256) void gibbs_kernel(const float* __restrict__ reward,
                                                    const float* __restrict__ quadratic,
                                                    const float* __restrict__ bvec,
                                                    const unsigned* __restrict__ keys,
                                                    float* __restrict__ out) {
#pragma clang fp contract(off)
  __shared__ float Wl[NNODES][NNODES];       // 16KB, read-only after prolog
  __shared__ float ubuf[4][4 * NHID];        // per-wave u staging [row][node'] (3KB)
  __shared__ f32x4 sbuf[4][NHID];            // per-wave state [node'] = {r0..r3} (3KB)

  const int tid = threadIdx.x;
  for (int i = tid; i < NNODES * NNODES; i += 256) {
    int k = i >> 6, j = i & 63;
    Wl[k][j] = quadratic[i] + quadratic[j * NNODES + k];  // exact f32 add
  }
  __syncthreads();

  const int wave = tid >> 6, lane = tid & 63;
  const int gw = blockIdx.x * 4 + wave;      // wave-global index
  const int r0 = gw * 4;                     // 4 consecutive rows per wave

  const float4 rw4 = ((const float4*)reward)[gw];
  const float bj = bvec[lane];
  f32x2 svA = sigmoid2_pk((f32x2){rw4.x * 2.0f, rw4.y * 2.0f});
  f32x2 svB = sigmoid2_pk((f32x2){rw4.z * 2.0f, rw4.w * 2.0f});

  // W column: hidden rows as pairs; visible prefix folded into acc16 (k=0..15 in order)
  f32x2 wp[24];
#pragma unroll
  for (int i = 0; i < 24; ++i) {
    f32x2 w; w.x = Wl[16 + 2 * i][lane]; w.y = Wl[17 + 2 * i][lane];
    wp[i] = w;
  }
  f32x2 acc16A = (f32x2)0.0f, acc16B = (f32x2)0.0f;
#pragma unroll
  for (int i = 0; i < 8; ++i) {
    f32x2 w; w.x = Wl[2 * i][lane]; w.y = Wl[2 * i + 1][lane];
    acc16A = pk_fma_lo(svA, w, acc16A);
    acc16A = pk_fma_hi(svA, w, acc16A);
    acc16B = pk_fma_lo(svB, w, acc16B);
    acc16B = pk_fma_hi(svB, w, acc16B);
  }

  // producer routing: draw idx = c*64 + lane -> (row rr, hidden node jj); step-invariant
  uint32_t nn[3];            // scan counters: (r0+rr)*64 + 16 + jj   (shape B x 64)
  float*   uw[3];            // ubuf write slots [rr][jj]
  float*   s0p[3];           // init state write slots [jj].component rr
  uint32_t ni[3];            // init counters: (r0+rr)*48 + jj        (shape B x 48)
#pragma unroll
  for (int c = 0; c < 3; ++c) {
    int idx = c * 64 + lane;
    int rr = (idx * 683) >> 15;            // idx / 48 for idx < 192
    int jj = idx - rr * 48;
    nn[c] = (uint32_t)((r0 + rr) * NNODES + NVIS + jj);
    ni[c] = (uint32_t)((r0 + rr) * NHID + jj);
    uw[c]  = &ubuf[wave][rr * NHID + jj];
    s0p[c] = ((float*)&sbuf[wave][0]) + (jj * 4 + rr);
  }

  // hidden0 = bernoulli(k_init, 0.5): bit = (rbits32 >> 31) == 0; 192 draws = 3 ciphers
  {
    const uint32_t ki0 = keys[0], ki1 = keys[1];
#pragma unroll
    for (int c = 0; c < 3; ++c) {
      uint32_t b = rbits32(ki0, ki1, ni[c]);
      *s0p[c] = (b >> 31) ? 0.0f : 1.0f;
    }
  }

  const bool isvis = (lane < NVIS);
  const int jc = isvis ? 0 : lane - NVIS;
  f32x2 scurA = svA, scurB = svB;          // visible lanes keep sv forever
  const float* ub = ubuf[wave];
  const f32x4* st = sbuf[wave];

  const uint2* kbuf = (const uint2*)(keys + 2);
  uint2 kk = kbuf[0];
#pragma unroll 1
  for (int t = 0; t < NSTEPS; ++t) {
    uint2 kn = kbuf[(t + 1 < NSTEPS) ? t + 1 : t];
    // 3 independent cipher chains (compiler interleaves for ILP)
    uint32_t b0 = rbits32(kk.x, kk.y, nn[0]);
    uint32_t b1 = rbits32(kk.x, kk.y, nn[1]);
    uint32_t b2 = rbits32(kk.x, kk.y, nn[2]);
    *uw[0] = __uint_as_float((b0 >> 9) | 0x3f800000u) - 1.0f;  // exact u01
    *uw[1] = __uint_as_float((b1 >> 9) | 0x3f800000u) - 1.0f;
    *uw[2] = __uint_as_float((b2 >> 9) | 0x3f800000u) - 1.0f;

    f32x2 aA, aB;
    dot4(st, wp, acc16A, acc16B, aA, aB);
    f32x2 pA = sigmoid2_pk(aA);            // b adds 0 to hidden units
    f32x2 pB = sigmoid2_pk(aB);

    f32x2 uA; uA.x = ub[jc];            uA.y = ub[NHID + jc];
    f32x2 uB; uB.x = ub[2 * NHID + jc]; uB.y = ub[3 * NHID + jc];
    if (!isvis) {
      scurA.x = (uA.x < pA.x) ? 1.0f : 0.0f;
      scurA.y = (uA.y < pA.y) ? 1.0f : 0.0f;
      scurB.x = (uB.x < pB.x) ? 1.0f : 0.0f;
      scurB.y = (uB.y < pB.y) ? 1.0f : 0.0f;
      f32x4 sq; sq.x = scurA.x; sq.y = scurA.y; sq.z = scurB.x; sq.w = scurB.y;
      sbuf[wave][jc] = sq;
    }
    kk = kn;
  }

  // energy: adjusted[r] = reward[r] + sum_j s_j*(0.5*a_j + b_j)   (loose tolerance)
  f32x2 aA, aB;
  dot4(st, wp, acc16A, acc16B, aA, aB);
  f32x2 bj2; bj2.x = bj; bj2.y = bj;
  const f32x2 half2 = (f32x2)0.5f;
  f32x2 cA = pk_mul2(scurA, pk_fma2(half2, aA, bj2));
  f32x2 cB = pk_mul2(scurB, pk_fma2(half2, aB, bj2));
  float c0 = cA.x, c1 = cA.y, c2 = cB.x, c3 = cB.y;
#pragma unroll
  for (int off = 32; off; off >>= 1) {
    c0 += __shfl_xor(c0, off);
    c1 += __shfl_xor(c1, off);
    c2 += __shfl_xor(c2, off);
    c3 += __shfl_xor(c3, off);
  }
  if (lane == 0) {
    ((float4*)out)[gw] = make_float4(rw4.x + c0, rw4.y + c1, rw4.z + c2, rw4.w + c3);
  }
}

extern "C" void kernel_launch(void* const* d_in, const int* in_sizes, int n_in,
                              void* d_out, int out_size, void* d_ws, size_t ws_size,
                              hipStream_t stream) {
  const float* emb    = (const float*)d_in[0];
  const float* reward = (const float*)d_in[1];
  const float* pca    = (const float*)d_in[2];
  const float* quad   = (const float*)d_in[3];
  float* out = (float*)d_out;

  int nblk = 1024;
  while (nblk > 4 &&
         ws_size < (size_t)nblk * EDIM * 4 + (size_t)64 * EDIM * 4 + 4096)
    nblk >>= 1;
  const int g2  = (nblk >= 64) ? 64 : nblk;
  const int per = nblk / g2;

  float*    partials = (float*)d_ws;
  float*    level2   = partials + (size_t)nblk * EDIM;
  float*    bvec     = level2 + (size_t)64 * EDIM;
  unsigned* keys     = (unsigned*)(bvec + NNODES);

  colsum_kernel<<<nblk, 512, 0, stream>>>((const float4*)emb, (float4*)partials, nblk);
  reduce_kernel<<<g2, 512, 0, stream>>>(partials, level2, per);
  prep_kernel<<<1, 512, 0, stream>>>(pca, level2, g2, bvec, keys);
  gibbs_kernel<<<BATCH / 16, 256, 0, stream>>>(reward, quad, bvec, keys, out);
}